// Round 7
// baseline (291.911 us; speedup 1.0000x reference)
//
#include <hip/hip_runtime.h>
#include <stdint.h>

typedef unsigned short u16;
typedef __bf16 bf16x8 __attribute__((ext_vector_type(8)));
typedef float f32x4 __attribute__((ext_vector_type(4)));
typedef float f32x16 __attribute__((ext_vector_type(16)));
typedef unsigned int u32;

// ---------------------------------------------------------------------------
// Weight "A-image" (u16 elems), 32x32x16-MFMA A-frag native granules:
//   elem[((koct*R + row)*8) + (k&7)],  koct = k>>3, R = rows.
//   L0    : kocts 0..13 (K=112: 96 enc + bias@96 + pad), R=128 -> 14336 elems
//   Hidden: kocts 0..29 (K=240: 128 hid + 96 enc + bias@224 + pad), R=128 -> 30720
//   Out   : kocts 0..29, R=32 (4 real rows) -> 7680
// ---------------------------------------------------------------------------
#define IMG_H(l) (14336 + ((l)-1) * 30720)
#define IMG_OUT 229376
#define IMG_TOTAL 237056

// hidden-feature k-position -> producing layer's C/D feature index.
__device__ inline int fmap(int k) {
    int s = k >> 4, h = (k >> 3) & 1, j = k & 7;
    return 32 * (s >> 1) + 16 * (s & 1) + 8 * (j >> 2) + 4 * h + (j & 3);
}
__device__ inline u16 b16rne(float v) {
    u32 u = __builtin_bit_cast(u32, v);
    u += 0x7FFFu + ((u >> 16) & 1u);
    return (u16)(u >> 16);
}

// ---------------------------------------------------------------------------
// Prep kernel: build bf16 A-image (fmap-permuted hidden cols, identity enc
// cols, bias folded at k=96/224, zero padding).
// ---------------------------------------------------------------------------
__global__ void nf_prep(const float* __restrict__ W0, const float* __restrict__ b0,
                        const float* __restrict__ Wh, const float* __restrict__ bh,
                        const float* __restrict__ Wl, const float* __restrict__ bl,
                        u16* __restrict__ img) {
    int idx = blockIdx.x * 256 + threadIdx.x;
    if (idx >= IMG_TOTAL) return;
    float v;
    if (idx < 14336) {                                    // layer 0
        int gg = idx >> 3, j = idx & 7;
        int koct = gg >> 7, i = gg & 127, k = koct * 8 + j;
        v = (k < 96) ? W0[k * 128 + i] : (k == 96) ? b0[i] : 0.f;
    } else if (idx < IMG_OUT) {                           // hidden 1..7
        int r = idx - 14336, l = r / 30720, rr = r % 30720;
        int gg = rr >> 3, j = rr & 7;
        int koct = gg >> 7, i = gg & 127, k = koct * 8 + j;
        const float* W = Wh + l * 224 * 128;
        v = (k < 128) ? W[fmap(k) * 128 + i]
          : (k < 224) ? W[k * 128 + i]
          : (k == 224) ? bh[l * 128 + i] : 0.f;
    } else {                                              // output layer
        int r = idx - IMG_OUT;
        int gg = r >> 3, j = r & 7;
        int koct = gg >> 5, i = gg & 31, k = koct * 8 + j;
        v = 0.f;
        if (i < 4)
            v = (k < 128) ? Wl[fmap(k) * 4 + i]
              : (k < 224) ? Wl[k * 4 + i]
              : (k == 224) ? bl[i] : 0.f;
    }
    img[idx] = b16rne(v);
}

// ---------------------------------------------------------------------------
// Main kernel helpers
// ---------------------------------------------------------------------------
__device__ inline f32x16 MF32(bf16x8 a, bf16x8 b, f32x16 c) {
    return __builtin_amdgcn_mfma_f32_32x32x16_bf16(a, b, c, 0, 0, 0);
}
__device__ inline bf16x8 fr4(const u32 (&p)[4]) {
    union { u32 u[4]; bf16x8 v; } x;
    x.u[0] = p[0]; x.u[1] = p[1]; x.u[2] = p[2]; x.u[3] = p[3];
    return x.v;
}
__device__ inline bf16x8 frCB(u32 c0) {
    union { u32 u[4]; bf16x8 v; } x;
    x.u[0] = c0; x.u[1] = 0; x.u[2] = 0; x.u[3] = 0;
    return x.v;
}
__device__ inline bf16x8 ldA(const u16* base, int gi) {   // ds_read_b128
    union { uint4 q; bf16x8 v; } x;
    x.q = *(const uint4*)(base + (gi << 3));
    return x.v;
}
// pack 2x f32 -> 2x bf16 (a->low, b->high).  PROVEN perm-based version.
// R4 lesson: v_cvt_pk_bf16_f32 inline asm broke numerics — do NOT swap.
__device__ inline u32 pkbf(float a, float b) {
    u32 ua = __builtin_bit_cast(u32, a) + 0x8000u;
    u32 ub = __builtin_bit_cast(u32, b) + 0x8000u;
    return __builtin_amdgcn_perm(ub, ua, 0x07060302u);
}
// async global->LDS stage, 16B/lane, 1KB chunks round-robined over 4 waves
__device__ inline void stageA(const u16* gsrc, u16* ldst, int bytes, int wave, int lane) {
    const char* gs = (const char*)gsrc + lane * 16;
    char* ls = (char*)ldst;
    for (int c = wave * 1024; c < bytes; c += 4096)
        __builtin_amdgcn_global_load_lds(
            (const __attribute__((address_space(1))) void*)(gs + c),
            (__attribute__((address_space(3))) void*)(ls + c), 16, 0, 0);
}
__device__ inline void zeroacc(f32x16 (&acc)[4]) {
#pragma unroll
    for (int t = 0; t < 4; t++)
#pragma unroll
        for (int r = 0; r < 16; r++) acc[t][r] = 0.f;
}
// ReLU + pack accumulators into next-layer B fragments (in-register handoff)
// R2/R3/R5 lesson: buildH stays sequential, post-MFMA, pre-barrier.
__device__ inline void buildH(const f32x16 (&acc)[4], u32 (&H)[8][4]) {
#pragma unroll
    for (int s = 0; s < 8; s++) {
        const int t = s >> 1, rb = (s & 1) * 8;
#pragma unroll
        for (int q = 0; q < 4; q++)
            H[s][q] = pkbf(fmaxf(acc[t][rb + 2 * q], 0.f),
                           fmaxf(acc[t][rb + 2 * q + 1], 0.f));
    }
}

// counted vmcnt + raw barrier; sched_barrier(0) pins everything (spill-safe).
#define WAITV(N) asm volatile("s_waitcnt vmcnt(" #N ")" ::: "memory")
#define BAR() do { __builtin_amdgcn_s_barrier(); __builtin_amdgcn_sched_barrier(0); } while (0)

// one s-step: 4 m-tiles x 1 n-tile = 4 MFMA, A from LDS granule
__device__ inline void mmS(const u16* A, int h, int m32, int sl,
                           bf16x8 B0, f32x16 (&acc)[4]) {
#pragma unroll
    for (int t = 0; t < 4; t++) {
        bf16x8 a = ldA(A, (2 * sl + h) * 128 + t * 32 + m32);
        acc[t] = MF32(a, B0, acc[t]);
    }
}

// --- per-granule compute phases (16KB granule = 4 s-steps = 16 MFMA) ---
__device__ inline void phH03(const u16* A, int h, int m32, f32x16 (&acc)[4],
                             const u32 (&H)[8][4]) {
    __builtin_amdgcn_s_setprio(1);
#pragma unroll
    for (int sl = 0; sl < 4; sl++) mmS(A, h, m32, sl, fr4(H[sl]), acc);
    __builtin_amdgcn_s_setprio(0);
}
__device__ inline void phH47(const u16* A, int h, int m32, f32x16 (&acc)[4],
                             const u32 (&H)[8][4]) {
    __builtin_amdgcn_s_setprio(1);
#pragma unroll
    for (int sl = 0; sl < 4; sl++) mmS(A, h, m32, sl, fr4(H[4 + sl]), acc);
    __builtin_amdgcn_s_setprio(0);
}
__device__ inline void phE01(const u16* A, int h, int m32, f32x16 (&acc)[4],
                             const u32 (&E)[3][2][4]) {
    __builtin_amdgcn_s_setprio(1);
#pragma unroll
    for (int sl = 0; sl < 4; sl++)
        mmS(A, h, m32, sl, fr4(E[sl >> 1][sl & 1]), acc);
    __builtin_amdgcn_s_setprio(0);
}
// 12KB granule = 3 s-steps: E[c2][0], E[c2][1], bias
__device__ inline void phE2b(const u16* A, int h, int m32, f32x16 (&acc)[4],
                             const u32 (&E)[3][2][4], u32 CB0) {
    __builtin_amdgcn_s_setprio(1);
    mmS(A, h, m32, 0, fr4(E[2][0]), acc);
    mmS(A, h, m32, 1, fr4(E[2][1]), acc);
    mmS(A, h, m32, 2, frCB(CB0), acc);
    __builtin_amdgcn_s_setprio(0);
}
// L0 granule A: s0-3 = E[c0][*], E[c1][*]   (identical body to phE01)
// L0 granule B: s4-6 = E[c2][*], bias       (identical body to phE2b)

// ---------------------------------------------------------------------------
// Main fused-MLP kernel — 3-waves/SIMD restructure.
// Block = 256 threads = 4 waves, 128 points/block (32 points/wave: ONE
// n-tile).  acc[4] = 64 AGPR (was 128) -> ~130-150 unified regs/wave ->
// 3 blocks/CU co-resident (was 2).  LDS ring: 3 slabs x 16KB = 48KB
// (144KB/CU at 3 blocks).  Granule = 8 kocts (4 s-steps); hidden layer =
// granules {A,B,C,D} = {4,4,4,3} chunks/wave.  Slab pointers ROTATE
// (4 granules/layer mod 3 slabs != 0) — uniform SGPR pointer swap, no
// dynamic indexing.  Depth-2 prefetch, counted vmcnt (hand-traced):
//   prologue 4+3 -> WAITV(3); steady WAITV(4); 12KB granule WAITV(3);
//   Out(ragged 4/4/4/3) WAITV(3); final WAITV(0).
// Rationale: at 2 waves/SIMD, MfmaUtil 51 + VALUBusy 39 are ADDITIVE
// (pipes serialize); 3rd wave gives the CU scheduler a filler wave so
// VALU hides under setprio-1 MFMA bursts (m114 mechanism).
// ---------------------------------------------------------------------------
__global__ __launch_bounds__(256, 3) void nf_main(const float* __restrict__ qp,
                                                  const u16* __restrict__ img,
                                                  float* __restrict__ out) {
    __shared__ alignas(16) u16 lds[3][8192];               // 3 x 16KB = 48KB
    const int tid = threadIdx.x, wave = tid >> 6, lane = tid & 63;
    const int m32 = lane & 31, h = lane >> 5;
    const int pbase = blockIdx.x * 128 + wave * 32;

    // small anti-phase entry skew (kept from R6; correctness-neutral)
    if ((blockIdx.x ^ (blockIdx.x >> 8)) & 1) __builtin_amdgcn_s_sleep(20);

    u16* p0 = &lds[0][0];
    u16* p1 = &lds[1][0];
    u16* p2 = &lds[2][0];

    stageA(img, p0, 16384, wave, lane);                    // L0 gA (kocts 0..7), 4 ch
    stageA(img + 8192, p1, 12288, wave, lane);             // L0 gB (kocts 8..13), 3 ch

    // ---- encoding fragments, computed ONCE, kept in registers ----
    u32 E[3][2][4];
    const float sc0 = h ? 128.0f : 0.5f;                   // 2^(8h-1) revolutions
#pragma unroll
    for (int c = 0; c < 3; c++) {
        float r = qp[(pbase + m32) * 3 + c] * sc0;
        float sn[8], cs[8];
#pragma unroll
        for (int t = 0; t < 8; t++) {
            float fr = __builtin_amdgcn_fractf(r);
            sn[t] = __builtin_amdgcn_sinf(fr);
            cs[t] = __builtin_amdgcn_cosf(fr);
            r = r * 2.0f;
        }
#pragma unroll
        for (int q = 0; q < 4; q++) {
            E[c][0][q] = pkbf(sn[2 * q], sn[2 * q + 1]);
            E[c][1][q] = pkbf(cs[2 * q], cs[2 * q + 1]);
        }
    }
    const u32 CB0 = (h == 0) ? 0x00003F80u : 0u;           // bf16(1.0) at j=0,h=0

    f32x16 acc[4];
    u32 H[8][4];
    zeroacc(acc);

    WAITV(3); BAR();                                       // gA certified (gB's 3 in flight)
    // ph0: compute L0 gA (s0-3: enc c0,c1); stage H1A
    stageA(img + IMG_H(1), p2, 16384, wave, lane);
    phE01(p0, h, m32, acc, E);
    WAITV(4); BAR();                                       // gB certified (H1A's 4 in flight)
    { u16* t = p0; p0 = p1; p1 = p2; p2 = t; }
    // ph1: compute L0 gB (s4-6: enc c2 + bias); stage H1B
    stageA(img + IMG_H(1) + 8192, p2, 16384, wave, lane);
    phE2b(p0, h, m32, acc, E, CB0);
    buildH(acc, H);
    WAITV(4); BAR();                                       // H1A certified
    { u16* t = p0; p0 = p1; p1 = p2; p2 = t; }

#pragma unroll 1
    for (int l = 1; l < 8; l++) {
        const int base = IMG_H(l);
        // P_A: granule lA (s0-3, H[0..3]); stage lC
        stageA(img + base + 16384, p2, 16384, wave, lane);
        zeroacc(acc);
        phH03(p0, h, m32, acc, H);
        WAITV(4); BAR();                                   // lB certified
        { u16* t = p0; p0 = p1; p1 = p2; p2 = t; }
        // P_B: granule lB (s4-7, H[4..7]); stage lD (12KB)
        stageA(img + base + 24576, p2, 12288, wave, lane);
        phH47(p0, h, m32, acc, H);
        WAITV(3); BAR();                                   // lC certified
        { u16* t = p0; p0 = p1; p1 = p2; p2 = t; }
        // P_C: granule lC (s8-11, enc c0,c1); stage (l+1)A or Out
        if (l < 7) stageA(img + IMG_H(l + 1), p2, 16384, wave, lane);
        else       stageA(img + IMG_OUT, p2, 15360, wave, lane);   // 4/4/4/3 ch
        phE01(p0, h, m32, acc, E);
        if (l < 7) { WAITV(4); } else { WAITV(3); }        // lD certified
        BAR();
        { u16* t = p0; p0 = p1; p1 = p2; p2 = t; }
        // P_D: granule lD (s12-14, enc c2 + bias); stage (l+1)B
        if (l < 7) stageA(img + IMG_H(l + 1) + 8192, p2, 16384, wave, lane);
        phE2b(p0, h, m32, acc, E, CB0);
        buildH(acc, H);
        if (l < 7) { WAITV(4); } else { WAITV(0); }        // (l+1)A / Out certified
        BAR();
        { u16* t = p0; p0 = p1; p1 = p2; p2 = t; }
    }

    // ---- output layer: one 32-row m-tile (rows 0..3 real), K=240, in p0 ----
    f32x16 o0;
#pragma unroll
    for (int r = 0; r < 16; r++) o0[r] = 0.f;
    __builtin_amdgcn_s_setprio(1);
#pragma unroll
    for (int s = 0; s < 15; s++) {
        bf16x8 B0;
        if (s < 8)       B0 = fr4(H[s]);
        else if (s < 14) B0 = fr4(E[(s - 8) >> 1][(s - 8) & 1]);
        else             B0 = frCB(CB0);
        bf16x8 a = ldA(p0, (2 * s + h) * 32 + m32);
        o0 = MF32(a, B0, o0);
    }
    __builtin_amdgcn_s_setprio(0);
    if (h == 0) {   // rows 0..3 live in regs 0..3 of the h=0 half
        f32x4 w0 = {o0[0], o0[1], o0[2], o0[3]};
        *(f32x4*)(out + 4 * (pbase + m32)) = w0;
    }
}

// ---------------------------------------------------------------------------
extern "C" void kernel_launch(void* const* d_in, const int* in_sizes, int n_in,
                              void* d_out, int out_size, void* d_ws, size_t ws_size,
                              hipStream_t stream) {
    const float* qp = (const float*)d_in[0];
    const float* W0 = (const float*)d_in[1];
    const float* b0 = (const float*)d_in[2];
    const float* Wh = (const float*)d_in[3];
    const float* bh = (const float*)d_in[4];
    const float* Wl = (const float*)d_in[5];
    const float* bl = (const float*)d_in[6];
    float* out = (float*)d_out;
    u16* img = (u16*)d_ws;   // 474,112 B needed

    nf_prep<<<926, 256, 0, stream>>>(W0, b0, Wh, bh, Wl, bl, img);
    nf_main<<<4096, 256, 0, stream>>>(qp, img, out);
}